// Round 1
// 86.894 us; speedup vs baseline: 1.0307x; 1.0307x over previous
//
#include <hip/hip_runtime.h>
#include <math.h>

constexpr int C = 512;
constexpr int H = 50;
constexpr int W = 75;
constexpr int NROI = 512;
constexpr int PLANE = H * W;        // 3750
constexpr int PPAD  = 3840;         // padded plane; px 3750..3839 zeroed (OOB corners, weight 0)
constexpr int NG = C / 4;           // 128 channel groups of 4
constexpr int RSPLIT = 4;           // was 16: 4x less plane restaging
constexpr int RPB = NROI / RSPLIT;  // 128 ROIs per block
constexpr int THREADS = 1024;       // 16 waves/block
constexpr float INV_STRIDE = 1.0f / 16.0f;

typedef _Float16 h2 __attribute__((ext_vector_type(2)));
struct alignas(8) px4 { h2 a, b; }; // one pixel, 4 packed fp16 channels (8 B)

// ---------------------------------------------------------------------------
// Single fused kernel: block = (4-ch group g, 128-ROI chunk), 512 blocks x
// 1024 threads, 59.4 KB LDS -> 2 blocks/CU -> 32 waves/CU (8/SIMD cap),
// exactly one scheduling round (512 = 256 CU x 2).
//
// vs the 89.6us RSPLIT=16 version: 1024-thread blocks escape the 40 KB/block
// LDS budget that forced RPB=32, so each plane is staged 4x instead of 16x
// (123 MB -> 31 MB staged reads) and per-ROI descriptors are built 4x128
// instead of 16x128 times. Inner gather/lerp loop is unchanged — it issues
// all 8 ds_read2_b64 gathers of an output quad before any math; LDS
// random-gather bank throughput + pk-fp16 VALU are the modeled floor.
// ---------------------------------------------------------------------------
__global__ __launch_bounds__(THREADS, 8) void roialign_fused(const float* __restrict__ bottom,
                                                             const float* __restrict__ rois,
                                                             float* __restrict__ out)
{
    __shared__ px4  plane[PPAD];         // 30720 B
    __shared__ uint4 xlds[RPB * 7];      // [rl][pw] = {offL, wL(h2 w0,w1), offR, wR}  14336 B
    __shared__ uint4 ylds[RPB * 7];      // [rl][ph] = {roffT, wT,          roffB, wB} 14336 B

    int g = blockIdx.x;
    int rbase = blockIdx.y * RPB;
    int t = threadIdx.x;

    // ---- fused staging: convert this block's 4 channels f32 -> px4 in LDS ----
    {
        const float* s0 = bottom + (4 * g + 0) * PLANE;
        const float* s1 = bottom + (4 * g + 1) * PLANE;
        const float* s2 = bottom + (4 * g + 2) * PLANE;
        const float* s3 = bottom + (4 * g + 3) * PLANE;
        for (int i = t; i < PPAD; i += THREADS) {
            px4 v;
            if (i < PLANE) {
                v.a = (h2){(_Float16)s0[i], (_Float16)s1[i]};
                v.b = (h2){(_Float16)s2[i], (_Float16)s3[i]};
            } else {
                v.a = (h2){(_Float16)0.0f, (_Float16)0.0f};
                v.b = v.a;
            }
            plane[i] = v;
        }
    }

    // ---- per-ROI interpolation descriptors (same math as all passing rounds) ----
    {
        uint2* xl2 = (uint2*)xlds;
        uint2* yl2 = (uint2*)ylds;
        for (int e = t; e < RPB * 28; e += THREADS) {
            int rl = e / 28;
            int tt = e - rl * 28;
            bool isx = tt < 14;
            int j = isx ? tt : tt - 14;
            const float* r = rois + (rbase + rl) * 5;
            float lo = (isx ? r[1] : r[2]) * INV_STRIDE;
            float hi = (isx ? r[3] : r[4]) * INV_STRIDE;
            float cc = 0.5f * (lo + hi), dd = 0.5f * (hi - lo);
            float b = -1.0f + (2.0f / 13.0f) * (float)j;
            float x  = fmaf(dd, b, cc);
            float xf = floorf(x);
            int ix = (int)xf;
            float f = x - xf;
            int lim = isx ? (W - 1) : (H - 1);
            bool v0 = (ix >= 0) && (ix <= lim);
            bool v1 = (ix + 1 >= 0) && (ix + 1 <= lim);
            int off = min(max(ix, 0), lim) * (isx ? 1 : W);
            float w0 = v0 ? (1.0f - f) : 0.0f;
            float w1 = v1 ? f : 0.0f;
            h2 wboth = (h2){(_Float16)w0, (_Float16)w1};
            uint2 d;
            d.x = (unsigned)off;
            d.y = __builtin_bit_cast(unsigned, wboth);
            (isx ? xl2 : yl2)[rl * 14 + j] = d;
        }
    }
    __syncthreads();

    // ---- gather + bilinear + maxpool ----
    auto do_quad = [&](int s) {
        int rl  = s / 49;               // magic-mul
        int s49 = s - rl * 49;
        int ph  = s49 / 7;
        int pw  = s49 - ph * 7;

        uint4 xd = xlds[rl * 7 + pw];   // {offL, wL, offR, wR}
        uint4 yd = ylds[rl * 7 + ph];   // {roffT, wT, roffB, wB}

        // issue ALL 8 gathers first (4 samples x 2 ds_read2_b64)
        const px4* pTL = plane + (int)yd.x + (int)xd.x;
        const px4* pTR = plane + (int)yd.x + (int)xd.z;
        const px4* pBL = plane + (int)yd.z + (int)xd.x;
        const px4* pBR = plane + (int)yd.z + (int)xd.z;
        px4 tl0 = pTL[0], tl1 = pTL[1], tl2 = pTL[W], tl3 = pTL[W + 1];
        px4 tr0 = pTR[0], tr1 = pTR[1], tr2 = pTR[W], tr3 = pTR[W + 1];
        px4 bl0 = pBL[0], bl1 = pBL[1], bl2 = pBL[W], bl3 = pBL[W + 1];
        px4 br0 = pBR[0], br1 = pBR[1], br2 = pBR[W], br3 = pBR[W + 1];

        h2 wxL = __builtin_bit_cast(h2, xd.y);
        h2 wxR = __builtin_bit_cast(h2, xd.w);
        h2 wyT = __builtin_bit_cast(h2, yd.y);
        h2 wyB = __builtin_bit_cast(h2, yd.w);

        auto lerp2 = [](px4 q0, px4 q1, px4 q2, px4 q3, h2 wx, h2 wy) -> px4 {
            h2 wx0 = __builtin_shufflevector(wx, wx, 0, 0);
            h2 wx1 = __builtin_shufflevector(wx, wx, 1, 1);
            h2 wy0 = __builtin_shufflevector(wy, wy, 0, 0);
            h2 wy1 = __builtin_shufflevector(wy, wy, 1, 1);
            px4 v;
            v.a = wy0 * (wx0 * q0.a + wx1 * q1.a) + wy1 * (wx0 * q2.a + wx1 * q3.a);
            v.b = wy0 * (wx0 * q0.b + wx1 * q1.b) + wy1 * (wx0 * q2.b + wx1 * q3.b);
            return v;
        };

        px4 vTL = lerp2(tl0, tl1, tl2, tl3, wxL, wyT);
        px4 vTR = lerp2(tr0, tr1, tr2, tr3, wxR, wyT);
        px4 vBL = lerp2(bl0, bl1, bl2, bl3, wxL, wyB);
        px4 vBR = lerp2(br0, br1, br2, br3, wxR, wyB);

        h2 ma = __builtin_elementwise_max(__builtin_elementwise_max(vTL.a, vTR.a),
                                          __builtin_elementwise_max(vBL.a, vBR.a));
        h2 mb = __builtin_elementwise_max(__builtin_elementwise_max(vTL.b, vTR.b),
                                          __builtin_elementwise_max(vBL.b, vBR.b));

        float* ob = out + (size_t)((rbase + rl) * C + 4 * g) * 49 + s49;
        ob[0]   = (float)ma.x;
        ob[49]  = (float)ma.y;
        ob[98]  = (float)mb.x;
        ob[147] = (float)mb.y;
    };

    // 6272 quads over 1024 threads: 6 full rounds + tail for t<128
    #pragma unroll
    for (int k = 0; k < 6; ++k) do_quad(t + k * THREADS);
    if (t < 128) do_quad(t + 6 * THREADS);
}

extern "C" void kernel_launch(void* const* d_in, const int* in_sizes, int n_in,
                              void* d_out, int out_size, void* d_ws, size_t ws_size,
                              hipStream_t stream) {
    const float* bottom = (const float*)d_in[0];
    const float* rois   = (const float*)d_in[1];
    float* out = (float*)d_out;

    dim3 grid(NG, RSPLIT); // 128 x 4 = 512 blocks, exactly 2/CU
    roialign_fused<<<grid, THREADS, 0, stream>>>(bottom, rois, out);
}